// Round 3
// baseline (290.337 us; speedup 1.0000x reference)
//
#include <hip/hip_runtime.h>
#include <stdint.h>

typedef __attribute__((ext_vector_type(8))) short short8;
typedef __attribute__((ext_vector_type(4))) float f32x4;

#define LOG2E 1.44269504088896f

__device__ __forceinline__ float bf2f(uint16_t u) {
    union { uint32_t i; float f; } v; v.i = ((uint32_t)u) << 16; return v.f;
}
__device__ __forceinline__ uint16_t f2bf(float f) {
    union { float f; uint32_t i; } v; v.f = f;
    return (uint16_t)((v.i + 0x7fffu + ((v.i >> 16) & 1u)) >> 16);
}

// ---------------- cast f32 -> bf16 (vectorized) ----------------
__global__ void cast_kernel(const float4* __restrict__ in, uint64_t* __restrict__ out, int n4) {
    int stride = gridDim.x * blockDim.x;
    for (int i = blockIdx.x * blockDim.x + threadIdx.x; i < n4; i += stride) {
        float4 v = in[i];
        uint64_t o = (uint64_t)f2bf(v.x) | ((uint64_t)f2bf(v.y) << 16)
                   | ((uint64_t)f2bf(v.z) << 32) | ((uint64_t)f2bf(v.w) << 48);
        out[i] = o;
    }
}

// ---------------- rope cos/sin table: tab[l*32+i] ----------------
__global__ void rope_table_kernel(float2* __restrict__ tab) {
    int idx = blockIdx.x * 256 + threadIdx.x;   // 65536 total
    int l = idx >> 5, i = idx & 31;
    float fr = powf(10000.0f, -(float)i * (1.0f / 32.0f));
    float ang = (float)l * fr;
    float s, c;
    sincosf(ang, &s, &c);
    tab[idx] = make_float2(c, s);
}

// ---------------- bf16 NT GEMM: C[M,N] = A[M,K] * B[N,K]^T + bias ----------------
// 128x128 tile, BK=64, 256 threads (4 waves), global_load_lds w/ source XOR swizzle.
template<bool OUTBF>
__global__ __launch_bounds__(256, 2) void gemm_bt(
    const uint16_t* __restrict__ A, const uint16_t* __restrict__ Bw,
    const float* __restrict__ bias, void* __restrict__ outp,
    int M, int N, int K)
{
    __shared__ uint16_t Asm[128 * 64];
    __shared__ uint16_t Bsm[128 * 64];
    int tid = threadIdx.x;
    int wave = tid >> 6, lane = tid & 63;
    int bm = blockIdx.y * 128, bn = blockIdx.x * 128;
    int wm = (wave >> 1) * 64, wn = (wave & 1) * 64;

    f32x4 acc[4][4] = {};

    int srow = lane >> 3;     // row within 8-row chunk
    int sc16 = lane & 7;      // 16B slot within 128B row

    for (int k0 = 0; k0 < K; k0 += 64) {
#pragma unroll
        for (int c = 0; c < 4; ++c) {
            int chunk = wave * 4 + c;
            int row = chunk * 8 + srow;
            int col = ((sc16 ^ (row & 7)) << 3);   // source pre-swizzle (elems)
            __builtin_amdgcn_global_load_lds(
                (const __attribute__((address_space(1))) void*)(A + (size_t)(bm + row) * K + k0 + col),
                (__attribute__((address_space(3))) void*)(Asm + chunk * 512),
                16, 0, 0);
            __builtin_amdgcn_global_load_lds(
                (const __attribute__((address_space(1))) void*)(Bw + (size_t)(bn + row) * K + k0 + col),
                (__attribute__((address_space(3))) void*)(Bsm + chunk * 512),
                16, 0, 0);
        }
        __syncthreads();
#pragma unroll
        for (int kk = 0; kk < 2; ++kk) {
            short8 af[4], bfr[4];
#pragma unroll
            for (int m = 0; m < 4; ++m) {
                int row = wm + m * 16 + (lane & 15);
                int kc = kk * 4 + (lane >> 4);
                af[m] = *(const short8*)(Asm + row * 64 + ((kc ^ (row & 7)) << 3));
            }
#pragma unroll
            for (int n = 0; n < 4; ++n) {
                int row = wn + n * 16 + (lane & 15);
                int kc = kk * 4 + (lane >> 4);
                bfr[n] = *(const short8*)(Bsm + row * 64 + ((kc ^ (row & 7)) << 3));
            }
#pragma unroll
            for (int m = 0; m < 4; ++m)
#pragma unroll
                for (int n = 0; n < 4; ++n)
                    acc[m][n] = __builtin_amdgcn_mfma_f32_16x16x32_bf16(af[m], bfr[n], acc[m][n], 0, 0, 0);
        }
        __syncthreads();
    }
#pragma unroll
    for (int m = 0; m < 4; ++m) {
#pragma unroll
        for (int n = 0; n < 4; ++n) {
            int col = bn + wn + n * 16 + (lane & 15);
            float bv = bias[col];
#pragma unroll
            for (int r = 0; r < 4; ++r) {
                int row = bm + wm + m * 16 + (lane >> 4) * 4 + r;
                float val = acc[m][n][r] + bv;
                if (OUTBF) ((uint16_t*)outp)[(size_t)row * N + col] = f2bf(val);
                else       ((float*)outp)[(size_t)row * N + col] = val;
            }
        }
    }
}

// ---------------- RoPE + RMSNorm; writes Q (pre-scaled by 1/8), K, V in [B][H][L][D] bf16 ----------------
__global__ void rope_rms_kernel(const uint16_t* __restrict__ qkv, const float2* __restrict__ tab,
                                const float* __restrict__ qg, const float* __restrict__ kg,
                                uint16_t* __restrict__ Q, uint16_t* __restrict__ Kk, uint16_t* __restrict__ V)
{
    int bl = blockIdx.x;          // b*2048 + l
    int h = blockIdx.y;
    int d = threadIdx.x;          // 0..63
    int l = bl & 2047;
    const uint16_t* base = qkv + (size_t)bl * 3072 + h * 64;
    size_t outoff = ((((size_t)(bl >> 11)) * 16 + h) * 2048 + l) * 64 + d;

    V[outoff] = base[2048 + d];   // raw bf16 passthrough

    float2 cs = tab[l * 32 + (d >> 1)];
    float sg = (d & 1) ? cs.y : -cs.y;
    {
        float t = bf2f(base[d]);
        float p = bf2f(base[d ^ 1]);
        float r = t * cs.x + p * sg;
        float ss = r * r;
#pragma unroll
        for (int m = 32; m >= 1; m >>= 1) ss += __shfl_xor(ss, m);
        float scale = rsqrtf(ss * (1.0f / 64.0f) + 1e-6f) * qg[h * 64 + d] * 0.125f;
        Q[outoff] = f2bf(r * scale);
    }
    {
        float t = bf2f(base[1024 + d]);
        float p = bf2f(base[1024 + (d ^ 1)]);
        float r = t * cs.x + p * sg;
        float ss = r * r;
#pragma unroll
        for (int m = 32; m >= 1; m >>= 1) ss += __shfl_xor(ss, m);
        float scale = rsqrtf(ss * (1.0f / 64.0f) + 1e-6f) * kg[h * 64 + d];
        Kk[outoff] = f2bf(r * scale);
    }
}

// ---------------- flash attention: 64 Q-rows / block, 4 waves x 16 rows, KV tile = 64 ----------------
__global__ __launch_bounds__(256, 2) void flash_kernel(
    const uint16_t* __restrict__ Q, const uint16_t* __restrict__ K, const uint16_t* __restrict__ V,
    uint16_t* __restrict__ O)
{
    __shared__ uint16_t Ksm[64 * 72];      // [kv][d], row pad -> 144B stride (16B aligned)
    __shared__ uint16_t Vsm[64 * 72];      // [d][kv] transposed
    __shared__ uint16_t Psm[4][16 * 72];   // per-wave [qrow][kv]
    int tid = threadIdx.x, wave = tid >> 6, lane = tid & 63;
    int bh = blockIdx.y;
    int q0 = blockIdx.x * 64;
    const uint16_t* Qb = Q + (size_t)bh * 2048 * 64;
    const uint16_t* Kb = K + (size_t)bh * 2048 * 64;
    const uint16_t* Vb = V + (size_t)bh * 2048 * 64;

    short8 qf[2];
    int qrow = q0 + wave * 16 + (lane & 15);
#pragma unroll
    for (int kk = 0; kk < 2; ++kk)
        qf[kk] = *(const short8*)(Qb + (size_t)qrow * 64 + kk * 32 + (lane >> 4) * 8);

    f32x4 oacc[4] = {};
    float mrow[4], lsum[4];
#pragma unroll
    for (int r = 0; r < 4; ++r) { mrow[r] = -1e30f; lsum[r] = 0.0f; }

    for (int kv0 = 0; kv0 < 2048; kv0 += 64) {
        {   // stage K [kv][d]: 64 rows x 8 slots of 8 elems; each thread does slots c and c+4
            int kv = tid >> 2, c = tid & 3;
            *(short8*)(Ksm + kv * 72 + c * 8) =
                *(const short8*)(Kb + (size_t)(kv0 + kv) * 64 + c * 8);
            *(short8*)(Ksm + kv * 72 + (c + 4) * 8) =
                *(const short8*)(Kb + (size_t)(kv0 + kv) * 64 + (c + 4) * 8);
        }
#pragma unroll
        for (int p = 0; p < 2; ++p) {   // stage V transposed [d][kv]
            int kv = tid & 63;
            int d0 = ((tid >> 6) + p * 4) * 8;
            short8 tv = *(const short8*)(Vb + (size_t)(kv0 + kv) * 64 + d0);
#pragma unroll
            for (int j = 0; j < 8; ++j)
                Vsm[(d0 + j) * 72 + kv] = (uint16_t)tv[j];
        }
        __syncthreads();

        // S = Q K^T  (16x64 per wave)
        f32x4 s[4] = {};
#pragma unroll
        for (int kk = 0; kk < 2; ++kk) {
            int kc = kk * 32 + (lane >> 4) * 8;
#pragma unroll
            for (int n = 0; n < 4; ++n) {
                short8 kf = *(const short8*)(Ksm + ((lane & 15) + n * 16) * 72 + kc);
                s[n] = __builtin_amdgcn_mfma_f32_16x16x32_bf16(qf[kk], kf, s[n], 0, 0, 0);
            }
        }
        // online softmax (rows = (lane>>4)*4 + r; cols spread over lane&15 and n)
        float alpha[4], rs[4];
#pragma unroll
        for (int r = 0; r < 4; ++r) {
            float v = fmaxf(fmaxf(s[0][r], s[1][r]), fmaxf(s[2][r], s[3][r]));
            v = fmaxf(v, __shfl_xor(v, 1));
            v = fmaxf(v, __shfl_xor(v, 2));
            v = fmaxf(v, __shfl_xor(v, 4));
            v = fmaxf(v, __shfl_xor(v, 8));
            float mn = fmaxf(mrow[r], v);
            alpha[r] = exp2f((mrow[r] - mn) * LOG2E);
            mrow[r] = mn;
            rs[r] = 0.0f;
        }
#pragma unroll
        for (int n = 0; n < 4; ++n)
#pragma unroll
            for (int r = 0; r < 4; ++r) {
                float p = exp2f((s[n][r] - mrow[r]) * LOG2E);
                rs[r] += p;
                Psm[wave][((lane >> 4) * 4 + r) * 72 + (lane & 15) + n * 16] = f2bf(p);
            }
        // ensure P writes are complete & ordered before the vector re-reads (same wave)
        asm volatile("s_waitcnt lgkmcnt(0)" ::: "memory");
#pragma unroll
        for (int r = 0; r < 4; ++r) {
            rs[r] += __shfl_xor(rs[r], 1);
            rs[r] += __shfl_xor(rs[r], 2);
            rs[r] += __shfl_xor(rs[r], 4);
            rs[r] += __shfl_xor(rs[r], 8);
            lsum[r] = lsum[r] * alpha[r] + rs[r];
        }
#pragma unroll
        for (int n = 0; n < 4; ++n)
#pragma unroll
            for (int r = 0; r < 4; ++r) oacc[n][r] *= alpha[r];

        // O += P V
#pragma unroll
        for (int kk2 = 0; kk2 < 2; ++kk2) {
            short8 pa = *(const short8*)(Psm[wave] + (lane & 15) * 72 + kk2 * 32 + (lane >> 4) * 8);
#pragma unroll
            for (int n = 0; n < 4; ++n) {
                short8 vf = *(const short8*)(Vsm + ((lane & 15) + n * 16) * 72 + kk2 * 32 + (lane >> 4) * 8);
                oacc[n] = __builtin_amdgcn_mfma_f32_16x16x32_bf16(pa, vf, oacc[n], 0, 0, 0);
            }
        }
        __syncthreads();
    }

    int b = bh >> 4, h = bh & 15;
#pragma unroll
    for (int r = 0; r < 4; ++r) {
        float inv = 1.0f / lsum[r];
        size_t row = (size_t)(b * 2048 + q0 + wave * 16 + (lane >> 4) * 4 + r);
#pragma unroll
        for (int n = 0; n < 4; ++n)
            O[row * 1024 + h * 64 + (lane & 15) + n * 16] = f2bf(oacc[n][r] * inv);
    }
}

extern "C" void kernel_launch(void* const* d_in, const int* in_sizes, int n_in,
                              void* d_out, int out_size, void* d_ws, size_t ws_size,
                              hipStream_t stream)
{
    const float* x      = (const float*)d_in[0];
    const float* w_qkv  = (const float*)d_in[1];
    const float* b_qkv  = (const float*)d_in[2];
    const float* w_out  = (const float*)d_in[3];
    const float* b_out  = (const float*)d_in[4];
    const float* qg     = (const float*)d_in[5];
    const float* kg     = (const float*)d_in[6];
    float* out = (float*)d_out;

    char* w = (char*)d_ws;
    uint16_t* x_bf    = (uint16_t*)w;  w += (size_t)4096 * 1024 * 2;
    uint16_t* wqkv_bf = (uint16_t*)w;  w += (size_t)3072 * 1024 * 2;
    uint16_t* wout_bf = (uint16_t*)w;  w += (size_t)1024 * 1024 * 2;
    float2*   tab     = (float2*)w;    w += (size_t)2048 * 32 * 8;
    uint16_t* qkv_bf  = (uint16_t*)w;  w += (size_t)4096 * 3072 * 2;
    uint16_t* Qb      = (uint16_t*)w;  w += (size_t)4096 * 1024 * 2;
    uint16_t* Kb      = (uint16_t*)w;  w += (size_t)4096 * 1024 * 2;
    uint16_t* Vb      = (uint16_t*)w;  w += (size_t)4096 * 1024 * 2;
    uint16_t* attn_bf = (uint16_t*)w;  w += (size_t)4096 * 1024 * 2;

    cast_kernel<<<2048, 256, 0, stream>>>((const float4*)x,     (uint64_t*)x_bf,    4096 * 1024 / 4);
    cast_kernel<<<2048, 256, 0, stream>>>((const float4*)w_qkv, (uint64_t*)wqkv_bf, 3072 * 1024 / 4);
    cast_kernel<<<1024, 256, 0, stream>>>((const float4*)w_out, (uint64_t*)wout_bf, 1024 * 1024 / 4);
    rope_table_kernel<<<256, 256, 0, stream>>>(tab);

    gemm_bt<true><<<dim3(24, 32), 256, 0, stream>>>(x_bf, wqkv_bf, b_qkv, qkv_bf, 4096, 3072, 1024);
    rope_rms_kernel<<<dim3(4096, 16), 64, 0, stream>>>(qkv_bf, tab, qg, kg, Qb, Kb, Vb);
    flash_kernel<<<dim3(32, 32), 256, 0, stream>>>(Qb, Kb, Vb, attn_bf);
    gemm_bt<false><<<dim3(8, 32), 256, 0, stream>>>(attn_bf, wout_bf, b_out, out, 4096, 1024, 1024);
}

// Round 4
// 217.508 us; speedup vs baseline: 1.3348x; 1.3348x over previous
//
#include <hip/hip_runtime.h>
#include <stdint.h>

typedef __attribute__((ext_vector_type(8))) short short8;
typedef __attribute__((ext_vector_type(4))) float f32x4;
typedef __attribute__((ext_vector_type(16))) float f32x16;

#define LOG2E 1.44269504088896f

__device__ __forceinline__ float bf2f(uint16_t u) {
    union { uint32_t i; float f; } v; v.i = ((uint32_t)u) << 16; return v.f;
}
__device__ __forceinline__ uint16_t f2bf(float f) {
    union { float f; uint32_t i; } v; v.f = f;
    return (uint16_t)((v.i + 0x7fffu + ((v.i >> 16) & 1u)) >> 16);
}

// ---------------- cast f32 -> bf16 (vectorized) ----------------
__global__ void cast_kernel(const float4* __restrict__ in, uint64_t* __restrict__ out, int n4) {
    int stride = gridDim.x * blockDim.x;
    for (int i = blockIdx.x * blockDim.x + threadIdx.x; i < n4; i += stride) {
        float4 v = in[i];
        uint64_t o = (uint64_t)f2bf(v.x) | ((uint64_t)f2bf(v.y) << 16)
                   | ((uint64_t)f2bf(v.z) << 32) | ((uint64_t)f2bf(v.w) << 48);
        out[i] = o;
    }
}

// ---------------- rope cos/sin table: tab[l*32+i] ----------------
__global__ void rope_table_kernel(float2* __restrict__ tab) {
    int idx = blockIdx.x * 256 + threadIdx.x;   // 65536 total
    int l = idx >> 5, i = idx & 31;
    float fr = powf(10000.0f, -(float)i * (1.0f / 32.0f));
    float ang = (float)l * fr;
    float s, c;
    sincosf(ang, &s, &c);
    tab[idx] = make_float2(c, s);
}

// ---------------- bf16 NT GEMM: C[M,N] = A[M,K] * B[N,K]^T + bias ----------------
template<bool OUTBF>
__global__ __launch_bounds__(256, 2) void gemm_bt(
    const uint16_t* __restrict__ A, const uint16_t* __restrict__ Bw,
    const float* __restrict__ bias, void* __restrict__ outp,
    int M, int N, int K)
{
    __shared__ uint16_t Asm[128 * 64];
    __shared__ uint16_t Bsm[128 * 64];
    int tid = threadIdx.x;
    int wave = tid >> 6, lane = tid & 63;
    int bm = blockIdx.y * 128, bn = blockIdx.x * 128;
    int wm = (wave >> 1) * 64, wn = (wave & 1) * 64;

    f32x4 acc[4][4] = {};

    int srow = lane >> 3;     // row within 8-row chunk
    int sc16 = lane & 7;      // 16B slot within 128B row

    for (int k0 = 0; k0 < K; k0 += 64) {
#pragma unroll
        for (int c = 0; c < 4; ++c) {
            int chunk = wave * 4 + c;
            int row = chunk * 8 + srow;
            int col = ((sc16 ^ (row & 7)) << 3);   // source pre-swizzle (elems)
            __builtin_amdgcn_global_load_lds(
                (const __attribute__((address_space(1))) void*)(A + (size_t)(bm + row) * K + k0 + col),
                (__attribute__((address_space(3))) void*)(Asm + chunk * 512),
                16, 0, 0);
            __builtin_amdgcn_global_load_lds(
                (const __attribute__((address_space(1))) void*)(Bw + (size_t)(bn + row) * K + k0 + col),
                (__attribute__((address_space(3))) void*)(Bsm + chunk * 512),
                16, 0, 0);
        }
        __syncthreads();
#pragma unroll
        for (int kk = 0; kk < 2; ++kk) {
            short8 af[4], bfr[4];
#pragma unroll
            for (int m = 0; m < 4; ++m) {
                int row = wm + m * 16 + (lane & 15);
                int kc = kk * 4 + (lane >> 4);
                af[m] = *(const short8*)(Asm + row * 64 + ((kc ^ (row & 7)) << 3));
            }
#pragma unroll
            for (int n = 0; n < 4; ++n) {
                int row = wn + n * 16 + (lane & 15);
                int kc = kk * 4 + (lane >> 4);
                bfr[n] = *(const short8*)(Bsm + row * 64 + ((kc ^ (row & 7)) << 3));
            }
#pragma unroll
            for (int m = 0; m < 4; ++m)
#pragma unroll
                for (int n = 0; n < 4; ++n)
                    acc[m][n] = __builtin_amdgcn_mfma_f32_16x16x32_bf16(af[m], bfr[n], acc[m][n], 0, 0, 0);
        }
        __syncthreads();
    }
#pragma unroll
    for (int m = 0; m < 4; ++m) {
#pragma unroll
        for (int n = 0; n < 4; ++n) {
            int col = bn + wn + n * 16 + (lane & 15);
            float bv = bias[col];
#pragma unroll
            for (int r = 0; r < 4; ++r) {
                int row = bm + wm + m * 16 + (lane >> 4) * 4 + r;
                float val = acc[m][n][r] + bv;
                if (OUTBF) ((uint16_t*)outp)[(size_t)row * N + col] = f2bf(val);
                else       ((float*)outp)[(size_t)row * N + col] = val;
            }
        }
    }
}

// ---------------- RoPE + RMSNorm; Q pre-scaled by (1/8)*log2(e); [B][H][L][D] bf16 ----------------
__global__ void rope_rms_kernel(const uint16_t* __restrict__ qkv, const float2* __restrict__ tab,
                                const float* __restrict__ qg, const float* __restrict__ kg,
                                uint16_t* __restrict__ Q, uint16_t* __restrict__ Kk, uint16_t* __restrict__ V)
{
    int bl = blockIdx.x;          // b*2048 + l
    int h = blockIdx.y;
    int d = threadIdx.x;          // 0..63
    int l = bl & 2047;
    const uint16_t* base = qkv + (size_t)bl * 3072 + h * 64;
    size_t outoff = ((((size_t)(bl >> 11)) * 16 + h) * 2048 + l) * 64 + d;

    V[outoff] = base[2048 + d];   // raw bf16 passthrough

    float2 cs = tab[l * 32 + (d >> 1)];
    float sg = (d & 1) ? cs.y : -cs.y;
    {
        float t = bf2f(base[d]);
        float p = bf2f(base[d ^ 1]);
        float r = t * cs.x + p * sg;
        float ss = r * r;
#pragma unroll
        for (int m = 32; m >= 1; m >>= 1) ss += __shfl_xor(ss, m);
        float scale = rsqrtf(ss * (1.0f / 64.0f) + 1e-6f) * qg[h * 64 + d] * (0.125f * LOG2E);
        Q[outoff] = f2bf(r * scale);
    }
    {
        float t = bf2f(base[1024 + d]);
        float p = bf2f(base[1024 + (d ^ 1)]);
        float r = t * cs.x + p * sg;
        float ss = r * r;
#pragma unroll
        for (int m = 32; m >= 1; m >>= 1) ss += __shfl_xor(ss, m);
        float scale = rsqrtf(ss * (1.0f / 64.0f) + 1e-6f) * kg[h * 64 + d];
        Kk[outoff] = f2bf(r * scale);
    }
}

// ---------------- flash attention: 128 q/block, 4 waves x 32 q, swapped-QK 32x32 MFMA ----------------
// S^T = mfma(K,Q): lane holds full kv-row for q=lane&31 (in-register softmax).
// O^T = mfma(V^T,P): per-lane alpha/lsum scale accumulator directly.
__global__ __launch_bounds__(256, 2) void flash_kernel(
    const uint16_t* __restrict__ Q, const uint16_t* __restrict__ K, const uint16_t* __restrict__ V,
    uint16_t* __restrict__ O)
{
    __shared__ __align__(16) uint16_t lds[16384];  // 32KB: Ksm[2][64][64] | Vsm[2][64][64] (Vt, swizzled)
    uint16_t* Ksm = lds;
    uint16_t* Vsm = lds + 8192;

    int tid = threadIdx.x, wave = tid >> 6, lane = tid & 63;
    int lq = lane & 31;    // q-column (QK/PV B-side n, C col); also d-row for V A-side
    int hi = lane >> 5;    // k-group half
    int bh = blockIdx.y;
    int q0 = blockIdx.x * 128 + wave * 32;
    const uint16_t* Qb = Q + (size_t)bh * 2048 * 64;
    const uint16_t* Kb = K + (size_t)bh * 2048 * 64;
    const uint16_t* Vb = V + (size_t)bh * 2048 * 64;

    // Q B-frags: qf[kb] = Q[q0+lq][kb*16 + hi*8 .. +7]
    short8 qf[4];
#pragma unroll
    for (int kb = 0; kb < 4; ++kb)
        qf[kb] = *(const short8*)(Qb + (size_t)(q0 + lq) * 64 + kb * 16 + hi * 8);

    f32x16 oacc0 = {}, oacc1 = {};
    float m = -1e30f, lsum = 0.0f;

    // staging thread roles
    int kvp = tid & 31, dg = tid >> 5;          // V: kv-pair, d-group(8)
    int r8 = lane >> 3, sl = lane & 7;          // K: row-in-chunk, slot
    int srccol = (sl ^ r8) << 3;                // K source pre-swizzle (elems)

    // prologue: stage K tile0 (buf0), load V tile0 regs
#pragma unroll
    for (int c = 0; c < 2; ++c) {
        int ch = wave * 2 + c;
        __builtin_amdgcn_global_load_lds(
            (const __attribute__((address_space(1))) void*)(Kb + (size_t)(ch * 8 + r8) * 64 + srccol),
            (__attribute__((address_space(3))) void*)(Ksm + ch * 512), 16, 0, 0);
    }
    short8 va  = *(const short8*)(Vb + (size_t)(kvp * 2) * 64 + dg * 8);
    short8 vb2 = *(const short8*)(Vb + (size_t)(kvp * 2 + 1) * 64 + dg * 8);

    int buf = 0;
    for (int t = 0; t < 32; ++t) {
        // write Vt[buf] from regs: Vt[d][kv], slot-swizzled (slot = kv>>3 ^ (d&7))
        {
            char* Vbase = (char*)(Vsm + buf * 4096);
#pragma unroll
            for (int j = 0; j < 8; ++j) {
                uint32_t wd = (uint32_t)(uint16_t)va[j] | ((uint32_t)(uint16_t)vb2[j] << 16);
                *(uint32_t*)(Vbase + (dg * 8 + j) * 128 + (((kvp >> 2) ^ j) << 4) + ((kvp & 3) << 2)) = wd;
            }
        }
        __syncthreads();   // Vt visible; K[t] DMA drained

        if (t < 31) {      // prefetch tile t+1
            int kv0n = (t + 1) * 64;
#pragma unroll
            for (int c = 0; c < 2; ++c) {
                int ch = wave * 2 + c;
                __builtin_amdgcn_global_load_lds(
                    (const __attribute__((address_space(1))) void*)(Kb + (size_t)(kv0n + ch * 8 + r8) * 64 + srccol),
                    (__attribute__((address_space(3))) void*)(Ksm + (buf ^ 1) * 4096 + ch * 512), 16, 0, 0);
            }
            va  = *(const short8*)(Vb + (size_t)(kv0n + kvp * 2) * 64 + dg * 8);
            vb2 = *(const short8*)(Vb + (size_t)(kv0n + kvp * 2 + 1) * 64 + dg * 8);
        }

        // ---- QK^T (swapped): S^T tiles kv 0-31 (st0), 32-63 (st1) ----
        const uint16_t* Kbase = Ksm + buf * 4096;
        f32x16 st0 = {}, st1 = {};
#pragma unroll
        for (int kb = 0; kb < 4; ++kb) {
            int sw = ((hi + 2 * kb) ^ (lq & 7)) << 3;
            short8 kf0 = *(const short8*)(Kbase + lq * 64 + sw);
            short8 kf1 = *(const short8*)(Kbase + (32 + lq) * 64 + sw);
            st0 = __builtin_amdgcn_mfma_f32_32x32x16_bf16(kf0, qf[kb], st0, 0, 0, 0);
            st1 = __builtin_amdgcn_mfma_f32_32x32x16_bf16(kf1, qf[kb], st1, 0, 0, 0);
        }

        // ---- online softmax (exp2-domain; per-lane q row) ----
        float pm = st0[0];
#pragma unroll
        for (int i = 1; i < 16; ++i) pm = fmaxf(pm, st0[i]);
#pragma unroll
        for (int i = 0; i < 16; ++i) pm = fmaxf(pm, st1[i]);
        pm = fmaxf(pm, __shfl_xor(pm, 32));
        if (!__all(pm <= m + 8.0f)) {          // T13 defer-max
            float mn = fmaxf(m, pm);
            float alpha = exp2f(m - mn);
            m = mn;
            lsum *= alpha;
#pragma unroll
            for (int i = 0; i < 16; ++i) { oacc0[i] *= alpha; oacc1[i] *= alpha; }
        }
        float rs = 0.0f;
        uint32_t w0[4][2], w1[4][2];           // packed bf16 pairs per quad
#pragma unroll
        for (int qd = 0; qd < 4; ++qd) {
#pragma unroll
            for (int k2 = 0; k2 < 2; ++k2) {
                float a0 = exp2f(st0[qd * 4 + k2 * 2]     - m);
                float a1 = exp2f(st0[qd * 4 + k2 * 2 + 1] - m);
                rs += a0 + a1;
                asm("v_cvt_pk_bf16_f32 %0, %1, %2" : "=v"(w0[qd][k2]) : "v"(a0), "v"(a1));
                float b0 = exp2f(st1[qd * 4 + k2 * 2]     - m);
                float b1 = exp2f(st1[qd * 4 + k2 * 2 + 1] - m);
                rs += b0 + b1;
                asm("v_cvt_pk_bf16_f32 %0, %1, %2" : "=v"(w1[qd][k2]) : "v"(b0), "v"(b1));
            }
        }
        rs += __shfl_xor(rs, 32);
        lsum += rs;

        // ---- PV: O^T += V^T . P, 4 kv-chunks of 16 ----
#pragma unroll
        for (int c = 0; c < 4; ++c) {
            int s = c & 1;
            uint32_t A0, B0, A1, B1;
            if (c < 2) { A0 = w0[s * 2][0]; B0 = w0[s * 2 + 1][0]; A1 = w0[s * 2][1]; B1 = w0[s * 2 + 1][1]; }
            else       { A0 = w1[s * 2][0]; B0 = w1[s * 2 + 1][0]; A1 = w1[s * 2][1]; B1 = w1[s * 2 + 1][1]; }
            // cross-half redistribute: after swap, A'={own/partner per derivation}, B'={partner/own}
            asm volatile("v_permlane32_swap_b32 %0, %1" : "+v"(A0), "+v"(B0));
            asm volatile("v_permlane32_swap_b32 %0, %1" : "+v"(A1), "+v"(B1));
            union { uint32_t u[4]; short8 s8; } pu;
            pu.u[0] = A0; pu.u[1] = A1; pu.u[2] = B0; pu.u[3] = B1;
            int sw = ((2 * c + hi) ^ (lq & 7)) << 3;
            const uint16_t* Vbase = Vsm + buf * 4096;
            short8 vf0 = *(const short8*)(Vbase + lq * 64 + sw);
            short8 vf1 = *(const short8*)(Vbase + (32 + lq) * 64 + sw);
            oacc0 = __builtin_amdgcn_mfma_f32_32x32x16_bf16(vf0, pu.s8, oacc0, 0, 0, 0);
            oacc1 = __builtin_amdgcn_mfma_f32_32x32x16_bf16(vf1, pu.s8, oacc1, 0, 0, 0);
        }
        buf ^= 1;
    }

    // ---- epilogue: O^T -> per-wave padded LDS -> coalesced global ----
    __syncthreads();                            // all compute reads done; safe to overlay lds
    float inv = 1.0f / lsum;
    char* Osm = (char*)(lds + wave * 2304);     // [32 q][72 d] u16
#pragma unroll
    for (int qd = 0; qd < 4; ++qd) {
#pragma unroll
        for (int k2 = 0; k2 < 2; ++k2) {
            int dbase = 8 * qd + 4 * hi + 2 * k2;
            float p0 = oacc0[qd * 4 + k2 * 2] * inv, p1 = oacc0[qd * 4 + k2 * 2 + 1] * inv;
            uint32_t wd;
            asm("v_cvt_pk_bf16_f32 %0, %1, %2" : "=v"(wd) : "v"(p0), "v"(p1));
            *(uint32_t*)(Osm + lq * 144 + dbase * 2) = wd;
            float p2 = oacc1[qd * 4 + k2 * 2] * inv, p3 = oacc1[qd * 4 + k2 * 2 + 1] * inv;
            asm("v_cvt_pk_bf16_f32 %0, %1, %2" : "=v"(wd) : "v"(p2), "v"(p3));
            *(uint32_t*)(Osm + lq * 144 + (32 + dbase) * 2) = wd;
        }
    }
    asm volatile("s_waitcnt lgkmcnt(0)" ::: "memory");
    int q2 = lane >> 1, hf = lane & 1;
    char* OsmR = (char*)(lds + wave * 2304);
    size_t orow = (size_t)((bh >> 4) * 2048 + blockIdx.x * 128 + wave * 32 + q2) * 1024
                + (size_t)(bh & 15) * 64 + hf * 32;
#pragma unroll
    for (int ch = 0; ch < 4; ++ch) {
        short8 o = *(const short8*)(OsmR + q2 * 144 + hf * 64 + ch * 16);
        *(short8*)(O + orow + ch * 8) = o;
    }
}

extern "C" void kernel_launch(void* const* d_in, const int* in_sizes, int n_in,
                              void* d_out, int out_size, void* d_ws, size_t ws_size,
                              hipStream_t stream)
{
    const float* x      = (const float*)d_in[0];
    const float* w_qkv  = (const float*)d_in[1];
    const float* b_qkv  = (const float*)d_in[2];
    const float* w_out  = (const float*)d_in[3];
    const float* b_out  = (const float*)d_in[4];
    const float* qg     = (const float*)d_in[5];
    const float* kg     = (const float*)d_in[6];
    float* out = (float*)d_out;

    char* w = (char*)d_ws;
    uint16_t* x_bf    = (uint16_t*)w;  w += (size_t)4096 * 1024 * 2;
    uint16_t* wqkv_bf = (uint16_t*)w;  w += (size_t)3072 * 1024 * 2;
    uint16_t* wout_bf = (uint16_t*)w;  w += (size_t)1024 * 1024 * 2;
    float2*   tab     = (float2*)w;    w += (size_t)2048 * 32 * 8;
    uint16_t* qkv_bf  = (uint16_t*)w;  w += (size_t)4096 * 3072 * 2;
    uint16_t* Qb      = (uint16_t*)w;  w += (size_t)4096 * 1024 * 2;
    uint16_t* Kb      = (uint16_t*)w;  w += (size_t)4096 * 1024 * 2;
    uint16_t* Vb      = (uint16_t*)w;  w += (size_t)4096 * 1024 * 2;
    uint16_t* attn_bf = (uint16_t*)w;  w += (size_t)4096 * 1024 * 2;

    cast_kernel<<<2048, 256, 0, stream>>>((const float4*)x,     (uint64_t*)x_bf,    4096 * 1024 / 4);
    cast_kernel<<<2048, 256, 0, stream>>>((const float4*)w_qkv, (uint64_t*)wqkv_bf, 3072 * 1024 / 4);
    cast_kernel<<<1024, 256, 0, stream>>>((const float4*)w_out, (uint64_t*)wout_bf, 1024 * 1024 / 4);
    rope_table_kernel<<<256, 256, 0, stream>>>(tab);

    gemm_bt<true><<<dim3(24, 32), 256, 0, stream>>>(x_bf, wqkv_bf, b_qkv, qkv_bf, 4096, 3072, 1024);
    rope_rms_kernel<<<dim3(4096, 16), 64, 0, stream>>>(qkv_bf, tab, qg, kg, Qb, Kb, Vb);
    flash_kernel<<<dim3(16, 32), 256, 0, stream>>>(Qb, Kb, Vb, attn_bf);
    gemm_bt<false><<<dim3(8, 32), 256, 0, stream>>>(attn_bf, wout_bf, b_out, out, 4096, 1024, 1024);
}